// Round 8
// baseline (2605.215 us; speedup 1.0000x reference)
//
#include <hip/hip_runtime.h>
#include <hip/hip_bf16.h>

typedef __bf16 bf16_t;
typedef bf16_t bf16x8 __attribute__((ext_vector_type(8)));
typedef bf16_t bf16x4 __attribute__((ext_vector_type(4)));
typedef bf16_t bf16x2 __attribute__((ext_vector_type(2)));
typedef float f32x4 __attribute__((ext_vector_type(4)));
typedef float f32x2 __attribute__((ext_vector_type(2)));

// ---------------------------------------------------------------------------
// async global -> LDS, 16B per lane (wave-uniform LDS base, HW adds lane*16)
// ---------------------------------------------------------------------------
__device__ __forceinline__ void load_lds16(const bf16_t* g, bf16_t* l) {
  __builtin_amdgcn_global_load_lds(
      (const __attribute__((address_space(1))) unsigned int*)g,
      (__attribute__((address_space(3))) unsigned int*)l,
      16, 0, 0);
}

// ---------------------------------------------------------------------------
__global__ void conv_f32_bf16(const float* __restrict__ src,
                              bf16_t* __restrict__ dst, long n) {
  long i = ((long)blockIdx.x * blockDim.x + threadIdx.x) * 8;
  if (i + 7 >= n) return;
  float4 a = *(const float4*)(src + i);
  float4 b = *(const float4*)(src + i + 4);
  bf16x8 v;
  v[0] = (bf16_t)a.x; v[1] = (bf16_t)a.y; v[2] = (bf16_t)a.z; v[3] = (bf16_t)a.w;
  v[4] = (bf16_t)b.x; v[5] = (bf16_t)b.y; v[6] = (bf16_t)b.z; v[7] = (bf16_t)b.w;
  *(bf16x8*)(dst + i) = v;
}

__global__ void conv_bf16_f32(const bf16_t* __restrict__ src,
                              float* __restrict__ dst, long n) {
  long i = (long)blockIdx.x * blockDim.x + threadIdx.x;
  if (i >= n) return;
  dst[i] = (float)src[i];
}

__global__ void transpose_conv(const float* __restrict__ src,
                               bf16_t* __restrict__ dst, int Ksrc, int Nsrc) {
  __shared__ float tile[32][33];
  int n0 = blockIdx.x * 32, k0 = blockIdx.y * 32;
  int tx = threadIdx.x, ty = threadIdx.y;  // (32, 8)
#pragma unroll
  for (int i = 0; i < 32; i += 8)
    tile[ty + i][tx] = src[(long)(k0 + ty + i) * Nsrc + n0 + tx];
  __syncthreads();
#pragma unroll
  for (int i = 0; i < 32; i += 8)
    dst[(long)(n0 + ty + i) * Ksrc + k0 + tx] = (bf16_t)tile[tx][ty + i];
}

// ---------------------------------------------------------------------------
// m97-style GEMM: D[M,N] = A[M,K] @ Bt[N,K]^T + bias
// ---------------------------------------------------------------------------
template <int STORE_MODE>
__global__ __launch_bounds__(256) void gemm_bt_128(
    const bf16_t* __restrict__ A, const bf16_t* __restrict__ Bt,
    const float* __restrict__ bias, void* __restrict__ Dout,
    int M, int N, int K) {
  __shared__ bf16_t As[128 * 32];
  __shared__ bf16_t Bs[128 * 32];
  const int tid = threadIdx.x;
  const int lane = tid & 63;
  const int w = tid >> 6;
  const int wr = w >> 1, wc = w & 1;
  const int m0 = blockIdx.y * 128, n0 = blockIdx.x * 128;

  f32x4 acc[4][4] = {};

  const int r0 = tid >> 2;
  const int kk = (tid & 3) * 8;
  const int fr = lane & 15;
  const int fk = (lane >> 4) * 8;

  for (int k0 = 0; k0 < K; k0 += 32) {
    load_lds16(A + (long)(m0 + r0) * K + k0 + kk, As + w * 512);
    load_lds16(A + (long)(m0 + 64 + r0) * K + k0 + kk, As + 2048 + w * 512);
    load_lds16(Bt + (long)(n0 + r0) * K + k0 + kk, Bs + w * 512);
    load_lds16(Bt + (long)(n0 + 64 + r0) * K + k0 + kk, Bs + 2048 + w * 512);
    asm volatile("s_waitcnt vmcnt(0)" ::: "memory");
    __syncthreads();

    bf16x8 af[4], bfx[4];
#pragma unroll
    for (int m = 0; m < 4; ++m)
      af[m] = *(const bf16x8*)&As[(wr * 64 + m * 16 + fr) * 32 + fk];
#pragma unroll
    for (int n = 0; n < 4; ++n)
      bfx[n] = *(const bf16x8*)&Bs[(wc * 64 + n * 16 + fr) * 32 + fk];
#pragma unroll
    for (int m = 0; m < 4; ++m)
#pragma unroll
      for (int n = 0; n < 4; ++n)
        acc[m][n] = __builtin_amdgcn_mfma_f32_16x16x32_bf16(af[m], bfx[n],
                                                            acc[m][n], 0, 0, 0);
    __syncthreads();
  }

  const int fq = lane >> 4;
#pragma unroll
  for (int m = 0; m < 4; ++m) {
#pragma unroll
    for (int n = 0; n < 4; ++n) {
      int col = n0 + wc * 64 + n * 16 + fr;
      float bv = bias[col];
#pragma unroll
      for (int r = 0; r < 4; ++r) {
        int row = m0 + wr * 64 + m * 16 + fq * 4 + r;
        float v = acc[m][n][r] + bv;
        if (STORE_MODE == 0)
          ((float*)Dout)[(long)row * N + col] = v;
        else
          ((bf16_t*)Dout)[(long)row * N + col] = (bf16_t)v;
      }
    }
  }
}

// ---------------------------------------------------------------------------
// Persistent recurrence v6: 512 WGs (2 per CU -> hardware SMT latency hiding),
// 256 thr (4 waves).  Tile 16 rows x 32 cols; 8 independent row-group chains.
// gid: x=gid&7 (XCD under round-robin), s=gid>>3; g=(x&6)|(s>>5) (row group,
// lives on XCD pair {x&6, x&6|1}); i=(s&31)|((x&1)<<5) (col tile 0..63).
// The slot bit (s>>5) selects the group so the TWO co-resident WGs of a CU
// belong to DIFFERENT chains -> phases drift -> SMT hides handoff latency.
// W cols [n0,n0+16) in LDS (64 KB, staged once); cols [n0+16,n0+32) streamed
// from L2 each step -- issued BEFORE the poll (independent of producers).
// Per-wave producer flags: wave w drains its own 4 rows (vmcnt(0)) and flags
// immediately; consumer wave polls its 16 producer tiles x 4 waves = 64 flags
// (one per lane).  Coherence (proven r5/r6): h stores sc0sc1 write-through,
// A loads sc0 (L2-cacheable), relaxed agent flags, NO fences ever.
// ---------------------------------------------------------------------------
__global__ __launch_bounds__(256, 2) void rnn_persistent6(
    const bf16_t* __restrict__ h0,
    bf16_t* __restrict__ Hbuf,        // Z in, h out, (T,B,H) bf16
    const bf16_t* __restrict__ WhhT,  // (2048 cols, 2048 K) bf16
    unsigned int* __restrict__ flags) {  // 2048 flags, 64B apart, pre-zeroed
  __shared__ bf16_t Wlds[32768];      // 64 KB: elem ((k>>3)*16+col)*8 + (k&7)
  __shared__ float sred[4][16 * 36];  // 9.2 KB, padded stride 36

  const int tid = threadIdx.x, lane = tid & 63, w = tid >> 6;
  const int gid = blockIdx.x;
  const int x = gid & 7, s = gid >> 3;
  const int g = (x & 6) | (s >> 5);             // row group 0..7
  const int i = (s & 31) | ((x & 1) << 5);      // col tile 0..63
  const int m0 = g * 16, n0 = i * 32;
  const int H = 2048;
  const long BH = 128L * 2048;
  const int kb = w * 512;             // wave K-slab
  const int fr = lane & 15, fg = lane >> 4;

  // ---- stage W cols [n0, n0+16) into LDS (once) ----
  {
    const int scol = tid >> 4;          // 0..15
    const int sk8 = tid & 15;           // k8 base
    const bf16_t* gsrc = WhhT + (long)(n0 + scol) * H + sk8 * 8;
#pragma unroll 4
    for (int j = 0; j < 16; ++j) {
      bf16x8 v = *(const bf16x8*)(gsrc + j * 128);
      *(bf16x8*)&Wlds[((sk8 + j * 16) * 16 + scol) * 8] = v;
    }
  }
  __syncthreads();

  // epilogue ownership: 2 contiguous cols; wave w owns rows 4w..4w+3
  const int jj = tid * 2;
  const int zrow = jj >> 5, zcol = jj & 31;
  const int sidx = zrow * 36 + zcol;

  unsigned int* myflag = flags + (((((g << 6) | i) << 2) | w) << 4);
  const unsigned int* pollflag =
      flags + (((((g << 6) | (w * 16 + (lane >> 2))) << 2) | (lane & 3)) << 4);

  for (int t = 0; t < 256; ++t) {
    const bf16_t* hp = (t == 0) ? h0 : Hbuf + (long)(t - 1) * BH;
    bf16_t* z = Hbuf + (long)t * BH;
    const long zoff = (long)(m0 + zrow) * H + n0 + zcol;

    // ---- W-stream (cols n0+16..n0+32) + Z prefetch: NO producer dep,
    //      issued before the poll so their latency hides under the wait ----
    const bf16_t* Wg = WhhT + (long)(n0 + 16 + fr) * H + kb + fg * 8;
    f32x4 b0, b1, b2, b3, b4, b5, b6, b7, b8, b9, b10, b11, b12, b13, b14, b15;
    asm volatile(
        "global_load_dwordx4 %0, %16, off sc0\n\t"
        "global_load_dwordx4 %1, %16, off offset:64 sc0\n\t"
        "global_load_dwordx4 %2, %16, off offset:128 sc0\n\t"
        "global_load_dwordx4 %3, %16, off offset:192 sc0\n\t"
        "global_load_dwordx4 %4, %16, off offset:256 sc0\n\t"
        "global_load_dwordx4 %5, %16, off offset:320 sc0\n\t"
        "global_load_dwordx4 %6, %16, off offset:384 sc0\n\t"
        "global_load_dwordx4 %7, %16, off offset:448 sc0\n\t"
        "global_load_dwordx4 %8, %16, off offset:512 sc0\n\t"
        "global_load_dwordx4 %9, %16, off offset:576 sc0\n\t"
        "global_load_dwordx4 %10, %16, off offset:640 sc0\n\t"
        "global_load_dwordx4 %11, %16, off offset:704 sc0\n\t"
        "global_load_dwordx4 %12, %16, off offset:768 sc0\n\t"
        "global_load_dwordx4 %13, %16, off offset:832 sc0\n\t"
        "global_load_dwordx4 %14, %16, off offset:896 sc0\n\t"
        "global_load_dwordx4 %15, %16, off offset:960 sc0"
        : "=&v"(b0), "=&v"(b1), "=&v"(b2), "=&v"(b3), "=&v"(b4), "=&v"(b5),
          "=&v"(b6), "=&v"(b7), "=&v"(b8), "=&v"(b9), "=&v"(b10), "=&v"(b11),
          "=&v"(b12), "=&v"(b13), "=&v"(b14), "=&v"(b15)
        : "v"(Wg)
        : "memory");
    float zvr;
    {
      const bf16_t* zp = z + zoff;
      asm volatile("global_load_dword %0, %1, off sc0 sc1"
                   : "=v"(zvr)
                   : "v"(zp)
                   : "memory");
    }

    // ---- poll my K-slab's producers: 16 tiles x 4 waves = 64 flags ----
    if (t > 0) {
      unsigned int v;
      do {
        v = __hip_atomic_load(pollflag, __ATOMIC_RELAXED,
                              __HIP_MEMORY_SCOPE_AGENT);
        if (__all(v >= (unsigned int)t)) break;
        __builtin_amdgcn_s_sleep(1);
      } while (true);
    }

    // ---- A-frags: 16 rows (fr) x K-slab 512, sc0 (L2-cacheable) ----
    const bf16_t* Ab = hp + (long)(m0 + fr) * H + kb + fg * 8;
    f32x4 a0, a1, a2, a3, a4, a5, a6, a7, a8, a9, a10, a11, a12, a13, a14, a15;
    asm volatile(
        "global_load_dwordx4 %0, %16, off sc0\n\t"
        "global_load_dwordx4 %1, %16, off offset:64 sc0\n\t"
        "global_load_dwordx4 %2, %16, off offset:128 sc0\n\t"
        "global_load_dwordx4 %3, %16, off offset:192 sc0\n\t"
        "global_load_dwordx4 %4, %16, off offset:256 sc0\n\t"
        "global_load_dwordx4 %5, %16, off offset:320 sc0\n\t"
        "global_load_dwordx4 %6, %16, off offset:384 sc0\n\t"
        "global_load_dwordx4 %7, %16, off offset:448 sc0\n\t"
        "global_load_dwordx4 %8, %16, off offset:512 sc0\n\t"
        "global_load_dwordx4 %9, %16, off offset:576 sc0\n\t"
        "global_load_dwordx4 %10, %16, off offset:640 sc0\n\t"
        "global_load_dwordx4 %11, %16, off offset:704 sc0\n\t"
        "global_load_dwordx4 %12, %16, off offset:768 sc0\n\t"
        "global_load_dwordx4 %13, %16, off offset:832 sc0\n\t"
        "global_load_dwordx4 %14, %16, off offset:896 sc0\n\t"
        "global_load_dwordx4 %15, %16, off offset:960 sc0\n\t"
        "s_waitcnt vmcnt(0)"
        : "=&v"(a0), "=&v"(a1), "=&v"(a2), "=&v"(a3), "=&v"(a4), "=&v"(a5),
          "=&v"(a6), "=&v"(a7), "=&v"(a8), "=&v"(a9), "=&v"(a10), "=&v"(a11),
          "=&v"(a12), "=&v"(a13), "=&v"(a14), "=&v"(a15)
        : "v"(Ab)
        : "memory");
    __builtin_amdgcn_sched_barrier(0);  // keep MFMA after the wait

    f32x4 acc0 = {}, acc1 = {};
#define STEPX(ks, A, B)                                                       \
  {                                                                           \
    bf16x8 wl =                                                               \
        *(const bf16x8*)&Wlds[(((kb >> 3) + (ks) * 4 + fg) * 16 + fr) * 8];   \
    bf16x8 av = __builtin_bit_cast(bf16x8, A);                                \
    bf16x8 bv = __builtin_bit_cast(bf16x8, B);                                \
    acc0 = __builtin_amdgcn_mfma_f32_16x16x32_bf16(av, wl, acc0, 0, 0, 0);    \
    acc1 = __builtin_amdgcn_mfma_f32_16x16x32_bf16(av, bv, acc1, 0, 0, 0);    \
  }
    STEPX(0, a0, b0)    STEPX(1, a1, b1)    STEPX(2, a2, b2)
    STEPX(3, a3, b3)    STEPX(4, a4, b4)    STEPX(5, a5, b5)
    STEPX(6, a6, b6)    STEPX(7, a7, b7)    STEPX(8, a8, b8)
    STEPX(9, a9, b9)    STEPX(10, a10, b10) STEPX(11, a11, b11)
    STEPX(12, a12, b12) STEPX(13, a13, b13) STEPX(14, a14, b14)
    STEPX(15, a15, b15)
#undef STEPX

    // ---- cross-wave K-reduction (padded stride 36) ----
#pragma unroll
    for (int rr = 0; rr < 4; ++rr) {
      sred[w][(fg * 4 + rr) * 36 + fr] = acc0[rr];
      sred[w][(fg * 4 + rr) * 36 + 16 + fr] = acc1[rr];
    }
    __syncthreads();

    // ---- reduce 4 waves + Z + relu; sc0sc1 4B store; per-wave flag ----
    f32x2 r = *(const f32x2*)&sred[0][sidx];
    {
      f32x2 r1 = *(const f32x2*)&sred[1][sidx];
      f32x2 r2 = *(const f32x2*)&sred[2][sidx];
      f32x2 r3 = *(const f32x2*)&sred[3][sidx];
      r = r + r1 + r2 + r3;
    }
    bf16x2 zv = __builtin_bit_cast(bf16x2, zvr);
    bf16x2 o;
#pragma unroll
    for (int c2 = 0; c2 < 2; ++c2) {
      float v = r[c2] + (float)zv[c2];
      o[c2] = (bf16_t)(v > 0.f ? v : 0.f);
    }
    {
      float ov = __builtin_bit_cast(float, o);
      const bf16_t* zp = z + zoff;
      asm volatile("global_store_dword %0, %1, off sc0 sc1" ::"v"(zp),
                   "v"(ov)
                   : "memory");
    }
    asm volatile("s_waitcnt vmcnt(0)" ::: "memory");  // this wave's rows done
    if ((tid & 63) == 0)
      __hip_atomic_store(myflag, (unsigned int)(t + 1), __ATOMIC_RELAXED,
                         __HIP_MEMORY_SCOPE_AGENT);
    __syncthreads();  // sred WAR guard for next step
  }
}

// ---------------------------------------------------------------------------
extern "C" void kernel_launch(void* const* d_in, const int* in_sizes, int n_in,
                              void* d_out, int out_size, void* d_ws,
                              size_t ws_size, hipStream_t stream) {
  const float* x   = (const float*)d_in[0];  // (T,B,D)
  const float* h0  = (const float*)d_in[1];  // (B,H)
  const float* Wxh = (const float*)d_in[2];  // (D,H)
  const float* Whh = (const float*)d_in[3];  // (H,H)
  const float* bh  = (const float*)d_in[4];  // (H,)
  const float* Whq = (const float*)d_in[5];  // (H,Q)
  const float* bq  = (const float*)d_in[6];  // (Q,)
  float* out = (float*)d_out;

  const int T = 256, B = 128, D = 1024, H = 2048, Q = 1024;
  const long MB = (long)T * B;  // 32768

  char* ws = (char*)d_ws;
  unsigned int* flags = (unsigned int*)ws;  ws += 2048 * 64;  // padded flags
  bf16_t* x_bf = (bf16_t*)ws;  ws += MB * D * 2;              // 64 MiB
  bf16_t* Hbuf = (bf16_t*)ws;  ws += MB * H * 2;              // 128 MiB (Z->h)
  bf16_t* h0bf = (bf16_t*)ws;  ws += (long)B * H * 2;
  bf16_t* WxhT = (bf16_t*)ws;  ws += (long)H * D * 2;
  bf16_t* WhhT = (bf16_t*)ws;  ws += (long)H * H * 2;
  bf16_t* WhqT = (bf16_t*)ws;  ws += (long)Q * H * 2;

  hipMemsetAsync(flags, 0, 2048 * 64, stream);

  // --- convert inputs to bf16 (weights transposed to N x K) ---
  conv_f32_bf16<<<(int)(MB * D / 8 / 256), 256, 0, stream>>>(x, x_bf, MB * D);
  conv_f32_bf16<<<(int)((long)B * H / 8 / 256), 256, 0, stream>>>(h0, h0bf,
                                                                  (long)B * H);
  transpose_conv<<<dim3(H / 32, D / 32), dim3(32, 8), 0, stream>>>(Wxh, WxhT, D, H);
  transpose_conv<<<dim3(H / 32, H / 32), dim3(32, 8), 0, stream>>>(Whh, WhhT, H, H);
  transpose_conv<<<dim3(Q / 32, H / 32), dim3(32, 8), 0, stream>>>(Whq, WhqT, H, Q);

  // --- Z = x @ W_xh + b_h  (all timesteps), bf16 into Hbuf ---
  gemm_bt_128<1><<<dim3(H / 128, MB / 128), 256, 0, stream>>>(
      x_bf, WxhT, bh, Hbuf, (int)MB, H, D);

  // --- entire recurrence: ONE persistent kernel, 2 WGs/CU (SMT) ---
  rnn_persistent6<<<512, 256, 0, stream>>>(h0bf, Hbuf, WhhT, flags);

  // --- out = H @ W_hq + b_q  (fp32 straight to d_out) ---
  gemm_bt_128<0><<<dim3(Q / 128, MB / 128), 256, 0, stream>>>(
      Hbuf, WhqT, bq, out, (int)MB, Q, H);

  // --- final h (fp32) appended after (T*B, Q) block ---
  conv_bf16_f32<<<(int)((long)B * H / 256), 256, 0, stream>>>(
      Hbuf + (long)(T - 1) * B * H, out + MB * Q, (long)B * H);
}

// Round 9
// 2219.683 us; speedup vs baseline: 1.1737x; 1.1737x over previous
//
#include <hip/hip_runtime.h>
#include <hip/hip_bf16.h>

typedef __bf16 bf16_t;
typedef bf16_t bf16x8 __attribute__((ext_vector_type(8)));
typedef bf16_t bf16x4 __attribute__((ext_vector_type(4)));
typedef bf16_t bf16x2 __attribute__((ext_vector_type(2)));
typedef float f32x4 __attribute__((ext_vector_type(4)));
typedef float f32x2 __attribute__((ext_vector_type(2)));

// ---------------------------------------------------------------------------
// async global -> LDS, 16B per lane (wave-uniform LDS base, HW adds lane*16)
// ---------------------------------------------------------------------------
__device__ __forceinline__ void load_lds16(const bf16_t* g, bf16_t* l) {
  __builtin_amdgcn_global_load_lds(
      (const __attribute__((address_space(1))) unsigned int*)g,
      (__attribute__((address_space(3))) unsigned int*)l,
      16, 0, 0);
}

// ---------------------------------------------------------------------------
__global__ void conv_f32_bf16(const float* __restrict__ src,
                              bf16_t* __restrict__ dst, long n) {
  long i = ((long)blockIdx.x * blockDim.x + threadIdx.x) * 8;
  if (i + 7 >= n) return;
  float4 a = *(const float4*)(src + i);
  float4 b = *(const float4*)(src + i + 4);
  bf16x8 v;
  v[0] = (bf16_t)a.x; v[1] = (bf16_t)a.y; v[2] = (bf16_t)a.z; v[3] = (bf16_t)a.w;
  v[4] = (bf16_t)b.x; v[5] = (bf16_t)b.y; v[6] = (bf16_t)b.z; v[7] = (bf16_t)b.w;
  *(bf16x8*)(dst + i) = v;
}

__global__ void conv_bf16_f32(const bf16_t* __restrict__ src,
                              float* __restrict__ dst, long n) {
  long i = (long)blockIdx.x * blockDim.x + threadIdx.x;
  if (i >= n) return;
  dst[i] = (float)src[i];
}

__global__ void transpose_conv(const float* __restrict__ src,
                               bf16_t* __restrict__ dst, int Ksrc, int Nsrc) {
  __shared__ float tile[32][33];
  int n0 = blockIdx.x * 32, k0 = blockIdx.y * 32;
  int tx = threadIdx.x, ty = threadIdx.y;  // (32, 8)
#pragma unroll
  for (int i = 0; i < 32; i += 8)
    tile[ty + i][tx] = src[(long)(k0 + ty + i) * Nsrc + n0 + tx];
  __syncthreads();
#pragma unroll
  for (int i = 0; i < 32; i += 8)
    dst[(long)(n0 + ty + i) * Ksrc + k0 + tx] = (bf16_t)tile[tx][ty + i];
}

// ---------------------------------------------------------------------------
// m97-style GEMM: D[M,N] = A[M,K] @ Bt[N,K]^T + bias
// ---------------------------------------------------------------------------
template <int STORE_MODE>
__global__ __launch_bounds__(256) void gemm_bt_128(
    const bf16_t* __restrict__ A, const bf16_t* __restrict__ Bt,
    const float* __restrict__ bias, void* __restrict__ Dout,
    int M, int N, int K) {
  __shared__ bf16_t As[128 * 32];
  __shared__ bf16_t Bs[128 * 32];
  const int tid = threadIdx.x;
  const int lane = tid & 63;
  const int w = tid >> 6;
  const int wr = w >> 1, wc = w & 1;
  const int m0 = blockIdx.y * 128, n0 = blockIdx.x * 128;

  f32x4 acc[4][4] = {};

  const int r0 = tid >> 2;
  const int kk = (tid & 3) * 8;
  const int fr = lane & 15;
  const int fk = (lane >> 4) * 8;

  for (int k0 = 0; k0 < K; k0 += 32) {
    load_lds16(A + (long)(m0 + r0) * K + k0 + kk, As + w * 512);
    load_lds16(A + (long)(m0 + 64 + r0) * K + k0 + kk, As + 2048 + w * 512);
    load_lds16(Bt + (long)(n0 + r0) * K + k0 + kk, Bs + w * 512);
    load_lds16(Bt + (long)(n0 + 64 + r0) * K + k0 + kk, Bs + 2048 + w * 512);
    asm volatile("s_waitcnt vmcnt(0)" ::: "memory");
    __syncthreads();

    bf16x8 af[4], bfx[4];
#pragma unroll
    for (int m = 0; m < 4; ++m)
      af[m] = *(const bf16x8*)&As[(wr * 64 + m * 16 + fr) * 32 + fk];
#pragma unroll
    for (int n = 0; n < 4; ++n)
      bfx[n] = *(const bf16x8*)&Bs[(wc * 64 + n * 16 + fr) * 32 + fk];
#pragma unroll
    for (int m = 0; m < 4; ++m)
#pragma unroll
      for (int n = 0; n < 4; ++n)
        acc[m][n] = __builtin_amdgcn_mfma_f32_16x16x32_bf16(af[m], bfx[n],
                                                            acc[m][n], 0, 0, 0);
    __syncthreads();
  }

  const int fq = lane >> 4;
#pragma unroll
  for (int m = 0; m < 4; ++m) {
#pragma unroll
    for (int n = 0; n < 4; ++n) {
      int col = n0 + wc * 64 + n * 16 + fr;
      float bv = bias[col];
#pragma unroll
      for (int r = 0; r < 4; ++r) {
        int row = m0 + wr * 64 + m * 16 + fq * 4 + r;
        float v = acc[m][n][r] + bv;
        if (STORE_MODE == 0)
          ((float*)Dout)[(long)row * N + col] = v;
        else
          ((bf16_t*)Dout)[(long)row * N + col] = (bf16_t)v;
      }
    }
  }
}

// ---------------------------------------------------------------------------
// Persistent recurrence v7: XCD-closed row-group chains.
// 8 groups x 16 rows; row r of h_t depends ONLY on row r of h_{t-1}, so each
// group is a closed producer/consumer set.  g = gid&7 -> all 32 WGs of group
// g land on XCD g under measured round-robin dispatch (locality ONLY;
// protocol is mapping-independent).  WG tile: 16 rows x 64 cols (i = gid>>3).
// Wave w owns K-slab w*512.
// W cols [n0,n0+32) staged once in LDS (128 KB); cols [n0+32,n0+64) streamed
// to regs each step, ISSUED PRE-POLL (no producer dep -> latency hidden).
// Coherence (proven r5/r6): h stores sc0sc1 (write-through, L3-visible,
// never stale-cached); A loads sc0 (L2-allocating: first reader on the XCD
// fills the line from L3, remaining 31 readers hit local L2); Z prefetch
// sc0sc1; relaxed agent-scope flags; NO acquire/release fences anywhere.
// ---------------------------------------------------------------------------
__global__ __launch_bounds__(256, 1) void rnn_persistent7(
    const bf16_t* __restrict__ h0,
    bf16_t* __restrict__ Hbuf,        // Z in, h out, (T,B,H) bf16
    const bf16_t* __restrict__ WhhT,  // (2048 cols, 2048 K) bf16
    unsigned int* __restrict__ flags) {  // 256 flags, 64B apart, pre-zeroed
  __shared__ bf16_t Wlds[65536];      // 128 KB: elem ((k>>3)*32+col)*8 + (k&7)
  __shared__ float sred[4][16 * 68];  // 17.4 KB, padded stride 68

  const int tid = threadIdx.x, lane = tid & 63, w = tid >> 6;
  const int gid = blockIdx.x;
  const int g = gid & 7;              // row group == XCD (round-robin)
  const int i = gid >> 3;             // col tile 0..31
  const int m0 = g * 16, n0 = i * 64;
  const int H = 2048;
  const long BH = 128L * 2048;
  const int kb = w * 512;             // wave K-slab
  const int fr = lane & 15, fg = lane >> 4;
  const int w64 = w * 64;             // k8 base of this wave's slab

  // ---- stage W cols [n0, n0+32) into LDS (once) ----
  {
    const int scol = tid >> 3;          // 0..31
    const int sk = (tid & 7) * 8;       // k offset in 64-chunk
    const bf16_t* gsrc = WhhT + (long)(n0 + scol) * H + sk;
#pragma unroll 4
    for (int j = 0; j < 32; ++j) {
      bf16x8 v = *(const bf16x8*)(gsrc + j * 64);
      int k8 = j * 8 + (tid & 7);
      *(bf16x8*)&Wlds[(k8 * 32 + scol) * 8] = v;
    }
  }
  __syncthreads();

  // epilogue ownership: 4 contiguous cols per thread (16x64 tile = 1024)
  const int jj = tid * 4;
  const int zrow = jj >> 6, zcol = jj & 63;
  const int sidx = zrow * 68 + zcol;

  unsigned int* myflag = flags + ((g * 32 + i) << 4);
  const unsigned int* pollflag = flags + ((g * 32 + (lane & 31)) << 4);

  // streamed-W bases (cols n0+32+fr and n0+48+fr of this wave's K-slab)
  const bf16_t* Wg2 = WhhT + (long)(n0 + 32 + fr) * H + kb + fg * 8;
  const bf16_t* Wg3 = Wg2 + (long)16 * H;

  for (int t = 0; t < 256; ++t) {
    const bf16_t* hp = (t == 0) ? h0 : Hbuf + (long)(t - 1) * BH;
    bf16_t* z = Hbuf + (long)t * BH;
    const long zoff = (long)(m0 + zrow) * H + n0 + zcol;

    // ---- W-stream: 32 loads, NO producer dep, issued before the poll ----
    f32x4 b0, b1, b2, b3, b4, b5, b6, b7, b8, b9, b10, b11, b12, b13, b14, b15;
    f32x4 c0, c1, c2, c3, c4, c5, c6, c7, c8, c9, c10, c11, c12, c13, c14, c15;
#define WBLOB                                                                 \
  "global_load_dwordx4 %0, %16, off sc0\n\t"                                  \
  "global_load_dwordx4 %1, %16, off offset:64 sc0\n\t"                        \
  "global_load_dwordx4 %2, %16, off offset:128 sc0\n\t"                       \
  "global_load_dwordx4 %3, %16, off offset:192 sc0\n\t"                       \
  "global_load_dwordx4 %4, %16, off offset:256 sc0\n\t"                       \
  "global_load_dwordx4 %5, %16, off offset:320 sc0\n\t"                       \
  "global_load_dwordx4 %6, %16, off offset:384 sc0\n\t"                       \
  "global_load_dwordx4 %7, %16, off offset:448 sc0\n\t"                       \
  "global_load_dwordx4 %8, %16, off offset:512 sc0\n\t"                       \
  "global_load_dwordx4 %9, %16, off offset:576 sc0\n\t"                       \
  "global_load_dwordx4 %10, %16, off offset:640 sc0\n\t"                      \
  "global_load_dwordx4 %11, %16, off offset:704 sc0\n\t"                      \
  "global_load_dwordx4 %12, %16, off offset:768 sc0\n\t"                      \
  "global_load_dwordx4 %13, %16, off offset:832 sc0\n\t"                      \
  "global_load_dwordx4 %14, %16, off offset:896 sc0\n\t"                      \
  "global_load_dwordx4 %15, %16, off offset:960 sc0"
    asm volatile(WBLOB
                 : "=&v"(b0), "=&v"(b1), "=&v"(b2), "=&v"(b3), "=&v"(b4),
                   "=&v"(b5), "=&v"(b6), "=&v"(b7), "=&v"(b8), "=&v"(b9),
                   "=&v"(b10), "=&v"(b11), "=&v"(b12), "=&v"(b13), "=&v"(b14),
                   "=&v"(b15)
                 : "v"(Wg2)
                 : "memory");
    asm volatile(WBLOB
                 : "=&v"(c0), "=&v"(c1), "=&v"(c2), "=&v"(c3), "=&v"(c4),
                   "=&v"(c5), "=&v"(c6), "=&v"(c7), "=&v"(c8), "=&v"(c9),
                   "=&v"(c10), "=&v"(c11), "=&v"(c12), "=&v"(c13), "=&v"(c14),
                   "=&v"(c15)
                 : "v"(Wg3)
                 : "memory");
#undef WBLOB

    // Z prefetch: sc0 sc1 (no L2 allocation of not-yet-final lines)
    f32x2 zvr;
    {
      const bf16_t* zp = z + zoff;
      asm volatile("global_load_dwordx2 %0, %1, off sc0 sc1"
                   : "=v"(zvr)
                   : "v"(zp)
                   : "memory");
    }

    // ---- poll whole group's 32 flags (one per lane); intra-XCD fast ----
    if (t > 0) {
      unsigned int v;
      do {
        v = __hip_atomic_load(pollflag, __ATOMIC_RELAXED,
                              __HIP_MEMORY_SCOPE_AGENT);
        if (__all(v >= (unsigned int)t)) break;
        __builtin_amdgcn_s_sleep(1);
      } while (true);
    }

    // ---- A-frags: 16 rows (fr) x K-slab 512, sc0 (L2 shared fill) ----
    const bf16_t* Ab = hp + (long)(m0 + fr) * H + kb + fg * 8;
    f32x4 a0, a1, a2, a3, a4, a5, a6, a7, a8, a9, a10, a11, a12, a13, a14, a15;
    asm volatile(
        "global_load_dwordx4 %0, %16, off sc0\n\t"
        "global_load_dwordx4 %1, %16, off offset:64 sc0\n\t"
        "global_load_dwordx4 %2, %16, off offset:128 sc0\n\t"
        "global_load_dwordx4 %3, %16, off offset:192 sc0\n\t"
        "global_load_dwordx4 %4, %16, off offset:256 sc0\n\t"
        "global_load_dwordx4 %5, %16, off offset:320 sc0\n\t"
        "global_load_dwordx4 %6, %16, off offset:384 sc0\n\t"
        "global_load_dwordx4 %7, %16, off offset:448 sc0\n\t"
        "global_load_dwordx4 %8, %16, off offset:512 sc0\n\t"
        "global_load_dwordx4 %9, %16, off offset:576 sc0\n\t"
        "global_load_dwordx4 %10, %16, off offset:640 sc0\n\t"
        "global_load_dwordx4 %11, %16, off offset:704 sc0\n\t"
        "global_load_dwordx4 %12, %16, off offset:768 sc0\n\t"
        "global_load_dwordx4 %13, %16, off offset:832 sc0\n\t"
        "global_load_dwordx4 %14, %16, off offset:896 sc0\n\t"
        "global_load_dwordx4 %15, %16, off offset:960 sc0\n\t"
        "s_waitcnt vmcnt(0)"
        : "=&v"(a0), "=&v"(a1), "=&v"(a2), "=&v"(a3), "=&v"(a4), "=&v"(a5),
          "=&v"(a6), "=&v"(a7), "=&v"(a8), "=&v"(a9), "=&v"(a10), "=&v"(a11),
          "=&v"(a12), "=&v"(a13), "=&v"(a14), "=&v"(a15)
        : "v"(Ab)
        : "memory");
    __builtin_amdgcn_sched_barrier(0);  // keep MFMA after the wait

    f32x4 acc0 = {}, acc1 = {}, acc2 = {}, acc3 = {};
#define STEPX(ks, A, B, C)                                                    \
  {                                                                           \
    bf16x8 w0 = *(const bf16x8*)&Wlds[((w64 + (ks) * 4 + fg) * 32 + fr) * 8]; \
    bf16x8 w1 =                                                               \
        *(const bf16x8*)&Wlds[((w64 + (ks) * 4 + fg) * 32 + 16 + fr) * 8];    \
    bf16x8 av = __builtin_bit_cast(bf16x8, A);                                \
    bf16x8 g2 = __builtin_bit_cast(bf16x8, B);                                \
    bf16x8 g3 = __builtin_bit_cast(bf16x8, C);                                \
    acc0 = __builtin_amdgcn_mfma_f32_16x16x32_bf16(av, w0, acc0, 0, 0, 0);    \
    acc1 = __builtin_amdgcn_mfma_f32_16x16x32_bf16(av, w1, acc1, 0, 0, 0);    \
    acc2 = __builtin_amdgcn_mfma_f32_16x16x32_bf16(av, g2, acc2, 0, 0, 0);    \
    acc3 = __builtin_amdgcn_mfma_f32_16x16x32_bf16(av, g3, acc3, 0, 0, 0);    \
  }
    STEPX(0, a0, b0, c0)    STEPX(1, a1, b1, c1)    STEPX(2, a2, b2, c2)
    STEPX(3, a3, b3, c3)    STEPX(4, a4, b4, c4)    STEPX(5, a5, b5, c5)
    STEPX(6, a6, b6, c6)    STEPX(7, a7, b7, c7)    STEPX(8, a8, b8, c8)
    STEPX(9, a9, b9, c9)    STEPX(10, a10, b10, c10) STEPX(11, a11, b11, c11)
    STEPX(12, a12, b12, c12) STEPX(13, a13, b13, c13) STEPX(14, a14, b14, c14)
    STEPX(15, a15, b15, c15)
#undef STEPX

    // ---- cross-wave K-reduction (padded stride 68) ----
#pragma unroll
    for (int rr = 0; rr < 4; ++rr) {
      sred[w][(fg * 4 + rr) * 68 + fr] = acc0[rr];
      sred[w][(fg * 4 + rr) * 68 + 16 + fr] = acc1[rr];
      sred[w][(fg * 4 + rr) * 68 + 32 + fr] = acc2[rr];
      sred[w][(fg * 4 + rr) * 68 + 48 + fr] = acc3[rr];
    }
    __syncthreads();

    // ---- reduce 4 waves + Z + relu; sc0sc1 8B store ----
    f32x4 r = *(const f32x4*)&sred[0][sidx];
    {
      f32x4 r1 = *(const f32x4*)&sred[1][sidx];
      f32x4 r2 = *(const f32x4*)&sred[2][sidx];
      f32x4 r3 = *(const f32x4*)&sred[3][sidx];
      r = r + r1 + r2 + r3;
    }
    bf16x4 zv = __builtin_bit_cast(bf16x4, zvr);
    bf16x4 o;
#pragma unroll
    for (int c4 = 0; c4 < 4; ++c4) {
      float v = r[c4] + (float)zv[c4];
      o[c4] = (bf16_t)(v > 0.f ? v : 0.f);
    }
    {
      f32x2 ov = __builtin_bit_cast(f32x2, o);
      const bf16_t* zp = z + zoff;
      asm volatile("global_store_dwordx2 %0, %1, off sc0 sc1" ::"v"(zp),
                   "v"(ov)
                   : "memory");
    }
    asm volatile("s_waitcnt vmcnt(0)" ::: "memory");
    __syncthreads();  // all threads' stores drained; sred WAR-safe
    if (tid == 0)
      __hip_atomic_store(myflag, (unsigned int)(t + 1), __ATOMIC_RELAXED,
                         __HIP_MEMORY_SCOPE_AGENT);
  }
}

// ---------------------------------------------------------------------------
extern "C" void kernel_launch(void* const* d_in, const int* in_sizes, int n_in,
                              void* d_out, int out_size, void* d_ws,
                              size_t ws_size, hipStream_t stream) {
  const float* x   = (const float*)d_in[0];  // (T,B,D)
  const float* h0  = (const float*)d_in[1];  // (B,H)
  const float* Wxh = (const float*)d_in[2];  // (D,H)
  const float* Whh = (const float*)d_in[3];  // (H,H)
  const float* bh  = (const float*)d_in[4];  // (H,)
  const float* Whq = (const float*)d_in[5];  // (H,Q)
  const float* bq  = (const float*)d_in[6];  // (Q,)
  float* out = (float*)d_out;

  const int T = 256, B = 128, D = 1024, H = 2048, Q = 1024;
  const long MB = (long)T * B;  // 32768

  char* ws = (char*)d_ws;
  unsigned int* flags = (unsigned int*)ws;  ws += 256 * 64;  // padded flags
  bf16_t* x_bf = (bf16_t*)ws;  ws += MB * D * 2;             // 64 MiB
  bf16_t* Hbuf = (bf16_t*)ws;  ws += MB * H * 2;             // 128 MiB (Z->h)
  bf16_t* h0bf = (bf16_t*)ws;  ws += (long)B * H * 2;
  bf16_t* WxhT = (bf16_t*)ws;  ws += (long)H * D * 2;
  bf16_t* WhhT = (bf16_t*)ws;  ws += (long)H * H * 2;
  bf16_t* WhqT = (bf16_t*)ws;  ws += (long)Q * H * 2;

  hipMemsetAsync(flags, 0, 256 * 64, stream);

  // --- convert inputs to bf16 (weights transposed to N x K) ---
  conv_f32_bf16<<<(int)(MB * D / 8 / 256), 256, 0, stream>>>(x, x_bf, MB * D);
  conv_f32_bf16<<<(int)((long)B * H / 8 / 256), 256, 0, stream>>>(h0, h0bf,
                                                                  (long)B * H);
  transpose_conv<<<dim3(H / 32, D / 32), dim3(32, 8), 0, stream>>>(Wxh, WxhT, D, H);
  transpose_conv<<<dim3(H / 32, H / 32), dim3(32, 8), 0, stream>>>(Whh, WhhT, H, H);
  transpose_conv<<<dim3(Q / 32, H / 32), dim3(32, 8), 0, stream>>>(Whq, WhqT, H, Q);

  // --- Z = x @ W_xh + b_h  (all timesteps), bf16 into Hbuf ---
  gemm_bt_128<1><<<dim3(H / 128, MB / 128), 256, 0, stream>>>(
      x_bf, WxhT, bh, Hbuf, (int)MB, H, D);

  // --- entire recurrence: ONE persistent kernel, XCD-closed groups ---
  rnn_persistent7<<<256, 256, 0, stream>>>(h0bf, Hbuf, WhhT, flags);

  // --- out = H @ W_hq + b_q  (fp32 straight to d_out) ---
  gemm_bt_128<0><<<dim3(Q / 128, MB / 128), 256, 0, stream>>>(
      Hbuf, WhqT, bq, out, (int)MB, Q, H);

  // --- final h (fp32) appended after (T*B, Q) block ---
  conv_bf16_f32<<<(int)((long)B * H / 256), 256, 0, stream>>>(
      Hbuf + (long)(T - 1) * B * H, out + MB * Q, (long)B * H);
}

// Round 10
// 1841.076 us; speedup vs baseline: 1.4151x; 1.2056x over previous
//
#include <hip/hip_runtime.h>
#include <hip/hip_bf16.h>

typedef __bf16 bf16_t;
typedef bf16_t bf16x8 __attribute__((ext_vector_type(8)));
typedef bf16_t bf16x4 __attribute__((ext_vector_type(4)));
typedef bf16_t bf16x2 __attribute__((ext_vector_type(2)));
typedef float f32x4 __attribute__((ext_vector_type(4)));
typedef float f32x2 __attribute__((ext_vector_type(2)));

// ---------------------------------------------------------------------------
// async global -> LDS, 16B per lane (wave-uniform LDS base, HW adds lane*16)
// ---------------------------------------------------------------------------
__device__ __forceinline__ void load_lds16(const bf16_t* g, bf16_t* l) {
  __builtin_amdgcn_global_load_lds(
      (const __attribute__((address_space(1))) unsigned int*)g,
      (__attribute__((address_space(3))) unsigned int*)l,
      16, 0, 0);
}

// ---------------------------------------------------------------------------
__global__ void conv_f32_bf16(const float* __restrict__ src,
                              bf16_t* __restrict__ dst, long n) {
  long i = ((long)blockIdx.x * blockDim.x + threadIdx.x) * 8;
  if (i + 7 >= n) return;
  float4 a = *(const float4*)(src + i);
  float4 b = *(const float4*)(src + i + 4);
  bf16x8 v;
  v[0] = (bf16_t)a.x; v[1] = (bf16_t)a.y; v[2] = (bf16_t)a.z; v[3] = (bf16_t)a.w;
  v[4] = (bf16_t)b.x; v[5] = (bf16_t)b.y; v[6] = (bf16_t)b.z; v[7] = (bf16_t)b.w;
  *(bf16x8*)(dst + i) = v;
}

__global__ void conv_bf16_f32(const bf16_t* __restrict__ src,
                              float* __restrict__ dst, long n) {
  long i = (long)blockIdx.x * blockDim.x + threadIdx.x;
  if (i >= n) return;
  dst[i] = (float)src[i];
}

__global__ void transpose_conv(const float* __restrict__ src,
                               bf16_t* __restrict__ dst, int Ksrc, int Nsrc) {
  __shared__ float tile[32][33];
  int n0 = blockIdx.x * 32, k0 = blockIdx.y * 32;
  int tx = threadIdx.x, ty = threadIdx.y;  // (32, 8)
#pragma unroll
  for (int i = 0; i < 32; i += 8)
    tile[ty + i][tx] = src[(long)(k0 + ty + i) * Nsrc + n0 + tx];
  __syncthreads();
#pragma unroll
  for (int i = 0; i < 32; i += 8)
    dst[(long)(n0 + ty + i) * Ksrc + k0 + tx] = (bf16_t)tile[tx][ty + i];
}

// ---------------------------------------------------------------------------
// m97-style GEMM: D[M,N] = A[M,K] @ Bt[N,K]^T + bias
// ---------------------------------------------------------------------------
template <int STORE_MODE>
__global__ __launch_bounds__(256) void gemm_bt_128(
    const bf16_t* __restrict__ A, const bf16_t* __restrict__ Bt,
    const float* __restrict__ bias, void* __restrict__ Dout,
    int M, int N, int K) {
  __shared__ bf16_t As[128 * 32];
  __shared__ bf16_t Bs[128 * 32];
  const int tid = threadIdx.x;
  const int lane = tid & 63;
  const int w = tid >> 6;
  const int wr = w >> 1, wc = w & 1;
  const int m0 = blockIdx.y * 128, n0 = blockIdx.x * 128;

  f32x4 acc[4][4] = {};

  const int r0 = tid >> 2;
  const int kk = (tid & 3) * 8;
  const int fr = lane & 15;
  const int fk = (lane >> 4) * 8;

  for (int k0 = 0; k0 < K; k0 += 32) {
    load_lds16(A + (long)(m0 + r0) * K + k0 + kk, As + w * 512);
    load_lds16(A + (long)(m0 + 64 + r0) * K + k0 + kk, As + 2048 + w * 512);
    load_lds16(Bt + (long)(n0 + r0) * K + k0 + kk, Bs + w * 512);
    load_lds16(Bt + (long)(n0 + 64 + r0) * K + k0 + kk, Bs + 2048 + w * 512);
    asm volatile("s_waitcnt vmcnt(0)" ::: "memory");
    __syncthreads();

    bf16x8 af[4], bfx[4];
#pragma unroll
    for (int m = 0; m < 4; ++m)
      af[m] = *(const bf16x8*)&As[(wr * 64 + m * 16 + fr) * 32 + fk];
#pragma unroll
    for (int n = 0; n < 4; ++n)
      bfx[n] = *(const bf16x8*)&Bs[(wc * 64 + n * 16 + fr) * 32 + fk];
#pragma unroll
    for (int m = 0; m < 4; ++m)
#pragma unroll
      for (int n = 0; n < 4; ++n)
        acc[m][n] = __builtin_amdgcn_mfma_f32_16x16x32_bf16(af[m], bfx[n],
                                                            acc[m][n], 0, 0, 0);
    __syncthreads();
  }

  const int fq = lane >> 4;
#pragma unroll
  for (int m = 0; m < 4; ++m) {
#pragma unroll
    for (int n = 0; n < 4; ++n) {
      int col = n0 + wc * 64 + n * 16 + fr;
      float bv = bias[col];
#pragma unroll
      for (int r = 0; r < 4; ++r) {
        int row = m0 + wr * 64 + m * 16 + fq * 4 + r;
        float v = acc[m][n][r] + bv;
        if (STORE_MODE == 0)
          ((float*)Dout)[(long)row * N + col] = v;
        else
          ((bf16_t*)Dout)[(long)row * N + col] = (bf16_t)v;
      }
    }
  }
}

// ---------------------------------------------------------------------------
// LDS half-barrier (4 waves): monotonic counter, release add / acquire spin.
// ---------------------------------------------------------------------------
__device__ __forceinline__ void half_bar(unsigned int* c, unsigned int target,
                                         int lane) {
  if (lane == 0)
    __hip_atomic_fetch_add(c, 1u, __ATOMIC_RELEASE,
                           __HIP_MEMORY_SCOPE_WORKGROUP);
  unsigned int v;
  do {
    v = __hip_atomic_load(c, __ATOMIC_ACQUIRE, __HIP_MEMORY_SCOPE_WORKGROUP);
    if (v >= target) break;
    __builtin_amdgcn_s_sleep(1);
  } while (true);
}

// ---------------------------------------------------------------------------
// Persistent recurrence v8: TWO independent chains per WG as separate
// wave-groups (true SMT overlap), ONE shared W-LDS copy.
// 256 WGs x 512 thr (8 waves).  p=(gid>>1)&3, n0idx=((gid&1)<<5)|(gid>>3):
// chains p and p+4 (16 rows each, on XCD pair {2p,2p+1} under round-robin),
// col slice [n0, n0+32) shared by both halves -> W slice 128 KB staged ONCE.
// Half h = waves 4h..4h+3 runs chain p+4h independently: poll (wave lw polls
// only its K-slab's 16 producer flags), A-blob sc0, 32 MFMA, LDS half-barrier
// (NOT __syncthreads -- keeps halves decoupled), fused Z+ReLU sc0sc1 store,
// per-half flag, post-flag self-prefetch (pulls own tile into local L2 so
// same-XCD consumers skip the L3 trip; correct under any mapping).
// Coherence protocol unchanged (proven r5/r6): no fences anywhere.
// ---------------------------------------------------------------------------
__global__ __launch_bounds__(512, 1) void rnn_persistent8(
    const bf16_t* __restrict__ h0,
    bf16_t* __restrict__ Hbuf,        // Z in, h out, (T,B,H) bf16
    const bf16_t* __restrict__ WhhT,  // (2048 cols, 2048 K) bf16
    unsigned int* __restrict__ flags) {  // 512 flags, 64B apart, pre-zeroed
  __shared__ bf16_t Wlds[65536];       // 128 KB: elem ((k8)*32+col)*8 + k&7
  __shared__ float sred[2][4][16 * 36];  // 18.4 KB
  __shared__ unsigned int barc[2];       // per-half barrier counters

  const int tid = threadIdx.x, lane = tid & 63, w = tid >> 6;
  const int h = w >> 2;               // half 0/1
  const int lw = w & 3;               // wave within half
  const int gid = blockIdx.x;
  const int p = (gid >> 1) & 3;
  const int n0idx = ((gid & 1) << 5) | (gid >> 3);  // 0..63
  const int chain = p + h * 4;        // row group 0..7
  const int m0 = chain * 16, n0 = n0idx * 32;
  const int H = 2048;
  const long BH = 128L * 2048;
  const int kb = lw * 512;            // wave K-slab
  const int fr = lane & 15, fg = lane >> 4;
  const int w64 = lw * 64;            // k8 base of slab

  // ---- stage W cols [n0, n0+32) into LDS (once, all 512 threads) ----
  {
    const int scol = tid >> 4;          // 0..31
    const int sk16 = tid & 15;
    const bf16_t* gsrc = WhhT + (long)(n0 + scol) * H + sk16 * 8;
#pragma unroll 4
    for (int j = 0; j < 16; ++j) {
      bf16x8 v = *(const bf16x8*)(gsrc + j * 128);
      int k8 = sk16 + j * 16;
      *(bf16x8*)&Wlds[(k8 * 32 + scol) * 8] = v;
    }
  }
  if (tid < 2) barc[tid] = 0;
  __syncthreads();  // ONLY whole-WG barrier; halves are decoupled after this

  // epilogue ownership within half: 2 contiguous cols (16x32 tile = 512)
  const int halftid = tid & 255;
  const int jj = halftid * 2;
  const int zrow = jj >> 5, zcol = jj & 31;
  const int sidx = zrow * 36 + zcol;

  unsigned int* myflag = flags + (((chain << 6) | n0idx) << 4);
  const unsigned int* pollflag =
      flags + (((chain << 6) | (lw * 16 + (lane & 15))) << 4);
  unsigned int* bc = &barc[h];

  for (int t = 0; t < 256; ++t) {
    const bf16_t* hp = (t == 0) ? h0 : Hbuf + (long)(t - 1) * BH;
    bf16_t* z = Hbuf + (long)t * BH;
    const long zoff = (long)(m0 + zrow) * H + n0 + zcol;

    // Z prefetch: sc0 sc1 (no L2 allocation of not-yet-final lines)
    float zvr;
    {
      const bf16_t* zp = z + zoff;
      asm volatile("global_load_dword %0, %1, off sc0 sc1"
                   : "=v"(zvr)
                   : "v"(zp)
                   : "memory");
    }

    // ---- poll my K-slab's 16 producer flags (per-wave, no barrier) ----
    if (t > 0) {
      unsigned int v;
      do {
        v = __hip_atomic_load(pollflag, __ATOMIC_RELAXED,
                              __HIP_MEMORY_SCOPE_AGENT);
        if (__all(v >= (unsigned int)t)) break;
        __builtin_amdgcn_s_sleep(1);
      } while (true);
    }

    // ---- A-frags: 16 rows (fr) x K-slab 512, sc0 (L2-cacheable) ----
    const bf16_t* Ab = hp + (long)(m0 + fr) * H + kb + fg * 8;
    f32x4 a0, a1, a2, a3, a4, a5, a6, a7, a8, a9, a10, a11, a12, a13, a14, a15;
    asm volatile(
        "global_load_dwordx4 %0, %16, off sc0\n\t"
        "global_load_dwordx4 %1, %16, off offset:64 sc0\n\t"
        "global_load_dwordx4 %2, %16, off offset:128 sc0\n\t"
        "global_load_dwordx4 %3, %16, off offset:192 sc0\n\t"
        "global_load_dwordx4 %4, %16, off offset:256 sc0\n\t"
        "global_load_dwordx4 %5, %16, off offset:320 sc0\n\t"
        "global_load_dwordx4 %6, %16, off offset:384 sc0\n\t"
        "global_load_dwordx4 %7, %16, off offset:448 sc0\n\t"
        "global_load_dwordx4 %8, %16, off offset:512 sc0\n\t"
        "global_load_dwordx4 %9, %16, off offset:576 sc0\n\t"
        "global_load_dwordx4 %10, %16, off offset:640 sc0\n\t"
        "global_load_dwordx4 %11, %16, off offset:704 sc0\n\t"
        "global_load_dwordx4 %12, %16, off offset:768 sc0\n\t"
        "global_load_dwordx4 %13, %16, off offset:832 sc0\n\t"
        "global_load_dwordx4 %14, %16, off offset:896 sc0\n\t"
        "global_load_dwordx4 %15, %16, off offset:960 sc0\n\t"
        "s_waitcnt vmcnt(0)"
        : "=&v"(a0), "=&v"(a1), "=&v"(a2), "=&v"(a3), "=&v"(a4), "=&v"(a5),
          "=&v"(a6), "=&v"(a7), "=&v"(a8), "=&v"(a9), "=&v"(a10), "=&v"(a11),
          "=&v"(a12), "=&v"(a13), "=&v"(a14), "=&v"(a15)
        : "v"(Ab)
        : "memory");
    __builtin_amdgcn_sched_barrier(0);  // keep MFMA after the wait

    f32x4 acc0 = {}, acc1 = {};
#define STEPX(ks, A)                                                          \
  {                                                                           \
    bf16x8 w0 = *(const bf16x8*)&Wlds[((w64 + (ks) * 4 + fg) * 32 + fr) * 8]; \
    bf16x8 w1 =                                                               \
        *(const bf16x8*)&Wlds[((w64 + (ks) * 4 + fg) * 32 + 16 + fr) * 8];    \
    bf16x8 av = __builtin_bit_cast(bf16x8, A);                                \
    acc0 = __builtin_amdgcn_mfma_f32_16x16x32_bf16(av, w0, acc0, 0, 0, 0);    \
    acc1 = __builtin_amdgcn_mfma_f32_16x16x32_bf16(av, w1, acc1, 0, 0, 0);    \
  }
    STEPX(0, a0)   STEPX(1, a1)   STEPX(2, a2)   STEPX(3, a3)
    STEPX(4, a4)   STEPX(5, a5)   STEPX(6, a6)   STEPX(7, a7)
    STEPX(8, a8)   STEPX(9, a9)   STEPX(10, a10) STEPX(11, a11)
    STEPX(12, a12) STEPX(13, a13) STEPX(14, a14) STEPX(15, a15)
#undef STEPX

    // ---- cross-wave K-reduction within the half (padded stride 36) ----
#pragma unroll
    for (int rr = 0; rr < 4; ++rr) {
      sred[h][lw][(fg * 4 + rr) * 36 + fr] = acc0[rr];
      sred[h][lw][(fg * 4 + rr) * 36 + 16 + fr] = acc1[rr];
    }
    half_bar(bc, (unsigned int)(2 * t + 1) * 4, lane);

    // ---- reduce 4 waves + Z + relu; sc0sc1 4B store ----
    f32x2 r = *(const f32x2*)&sred[h][0][sidx];
    {
      f32x2 r1 = *(const f32x2*)&sred[h][1][sidx];
      f32x2 r2 = *(const f32x2*)&sred[h][2][sidx];
      f32x2 r3 = *(const f32x2*)&sred[h][3][sidx];
      r = r + r1 + r2 + r3;
    }
    bf16x2 zv = __builtin_bit_cast(bf16x2, zvr);
    bf16x2 o;
#pragma unroll
    for (int c2 = 0; c2 < 2; ++c2) {
      float v = r[c2] + (float)zv[c2];
      o[c2] = (bf16_t)(v > 0.f ? v : 0.f);
    }
    const bf16_t* zp = z + zoff;
    {
      float ov = __builtin_bit_cast(float, o);
      asm volatile("global_store_dword %0, %1, off sc0 sc1" ::"v"(zp),
                   "v"(ov)
                   : "memory");
    }
    asm volatile("s_waitcnt vmcnt(0)" ::: "memory");  // my stores drained
    half_bar(bc, (unsigned int)(2 * t + 2) * 4, lane);  // whole half drained
    if (halftid == 0)
      __hip_atomic_store(myflag, (unsigned int)(t + 1), __ATOMIC_RELAXED,
                         __HIP_MEMORY_SCOPE_AGENT);
    // self-prefetch just-written tile into THIS XCD's L2 (best-effort;
    // same-XCD consumers then L2-hit instead of L3).  No wait.
    {
      float dummy;
      asm volatile("global_load_dword %0, %1, off sc0"
                   : "=&v"(dummy)
                   : "v"(zp)
                   : "memory");
    }
  }
}

// ---------------------------------------------------------------------------
extern "C" void kernel_launch(void* const* d_in, const int* in_sizes, int n_in,
                              void* d_out, int out_size, void* d_ws,
                              size_t ws_size, hipStream_t stream) {
  const float* x   = (const float*)d_in[0];  // (T,B,D)
  const float* h0  = (const float*)d_in[1];  // (B,H)
  const float* Wxh = (const float*)d_in[2];  // (D,H)
  const float* Whh = (const float*)d_in[3];  // (H,H)
  const float* bh  = (const float*)d_in[4];  // (H,)
  const float* Whq = (const float*)d_in[5];  // (H,Q)
  const float* bq  = (const float*)d_in[6];  // (Q,)
  float* out = (float*)d_out;

  const int T = 256, B = 128, D = 1024, H = 2048, Q = 1024;
  const long MB = (long)T * B;  // 32768

  char* ws = (char*)d_ws;
  unsigned int* flags = (unsigned int*)ws;  ws += 512 * 64;  // padded flags
  bf16_t* x_bf = (bf16_t*)ws;  ws += MB * D * 2;             // 64 MiB
  bf16_t* Hbuf = (bf16_t*)ws;  ws += MB * H * 2;             // 128 MiB (Z->h)
  bf16_t* h0bf = (bf16_t*)ws;  ws += (long)B * H * 2;
  bf16_t* WxhT = (bf16_t*)ws;  ws += (long)H * D * 2;
  bf16_t* WhhT = (bf16_t*)ws;  ws += (long)H * H * 2;
  bf16_t* WhqT = (bf16_t*)ws;  ws += (long)Q * H * 2;

  hipMemsetAsync(flags, 0, 512 * 64, stream);

  // --- convert inputs to bf16 (weights transposed to N x K) ---
  conv_f32_bf16<<<(int)(MB * D / 8 / 256), 256, 0, stream>>>(x, x_bf, MB * D);
  conv_f32_bf16<<<(int)((long)B * H / 8 / 256), 256, 0, stream>>>(h0, h0bf,
                                                                  (long)B * H);
  transpose_conv<<<dim3(H / 32, D / 32), dim3(32, 8), 0, stream>>>(Wxh, WxhT, D, H);
  transpose_conv<<<dim3(H / 32, H / 32), dim3(32, 8), 0, stream>>>(Whh, WhhT, H, H);
  transpose_conv<<<dim3(Q / 32, H / 32), dim3(32, 8), 0, stream>>>(Whq, WhqT, H, Q);

  // --- Z = x @ W_xh + b_h  (all timesteps), bf16 into Hbuf ---
  gemm_bt_128<1><<<dim3(H / 128, MB / 128), 256, 0, stream>>>(
      x_bf, WxhT, bh, Hbuf, (int)MB, H, D);

  // --- entire recurrence: ONE persistent kernel, 2 SMT chains per WG ---
  rnn_persistent8<<<256, 512, 0, stream>>>(h0bf, Hbuf, WhhT, flags);

  // --- out = H @ W_hq + b_q  (fp32 straight to d_out) ---
  gemm_bt_128<0><<<dim3(Q / 128, MB / 128), 256, 0, stream>>>(
      Hbuf, WhqT, bq, out, (int)MB, Q, H);

  // --- final h (fp32) appended after (T*B, Q) block ---
  conv_bf16_f32<<<(int)((long)B * H / 256), 256, 0, stream>>>(
      Hbuf + (long)(T - 1) * B * H, out + MB * Q, (long)B * H);
}

// Round 12
// 1762.047 us; speedup vs baseline: 1.4785x; 1.0449x over previous
//
#include <hip/hip_runtime.h>
#include <hip/hip_bf16.h>

typedef __bf16 bf16_t;
typedef bf16_t bf16x8 __attribute__((ext_vector_type(8)));
typedef bf16_t bf16x4 __attribute__((ext_vector_type(4)));
typedef bf16_t bf16x2 __attribute__((ext_vector_type(2)));
typedef float f32x4 __attribute__((ext_vector_type(4)));
typedef float f32x2 __attribute__((ext_vector_type(2)));

// ---------------------------------------------------------------------------
// async global -> LDS, 16B per lane (wave-uniform LDS base, HW adds lane*16)
// ---------------------------------------------------------------------------
__device__ __forceinline__ void load_lds16(const bf16_t* g, bf16_t* l) {
  __builtin_amdgcn_global_load_lds(
      (const __attribute__((address_space(1))) unsigned int*)g,
      (__attribute__((address_space(3))) unsigned int*)l,
      16, 0, 0);
}

// ---------------------------------------------------------------------------
__global__ void conv_f32_bf16(const float* __restrict__ src,
                              bf16_t* __restrict__ dst, long n) {
  long i = ((long)blockIdx.x * blockDim.x + threadIdx.x) * 8;
  if (i + 7 >= n) return;
  float4 a = *(const float4*)(src + i);
  float4 b = *(const float4*)(src + i + 4);
  bf16x8 v;
  v[0] = (bf16_t)a.x; v[1] = (bf16_t)a.y; v[2] = (bf16_t)a.z; v[3] = (bf16_t)a.w;
  v[4] = (bf16_t)b.x; v[5] = (bf16_t)b.y; v[6] = (bf16_t)b.z; v[7] = (bf16_t)b.w;
  *(bf16x8*)(dst + i) = v;
}

__global__ void conv_bf16_f32(const bf16_t* __restrict__ src,
                              float* __restrict__ dst, long n) {
  long i = (long)blockIdx.x * blockDim.x + threadIdx.x;
  if (i >= n) return;
  dst[i] = (float)src[i];
}

__global__ void transpose_conv(const float* __restrict__ src,
                               bf16_t* __restrict__ dst, int Ksrc, int Nsrc) {
  __shared__ float tile[32][33];
  int n0 = blockIdx.x * 32, k0 = blockIdx.y * 32;
  int tx = threadIdx.x, ty = threadIdx.y;  // (32, 8)
#pragma unroll
  for (int i = 0; i < 32; i += 8)
    tile[ty + i][tx] = src[(long)(k0 + ty + i) * Nsrc + n0 + tx];
  __syncthreads();
#pragma unroll
  for (int i = 0; i < 32; i += 8)
    dst[(long)(n0 + ty + i) * Ksrc + k0 + tx] = (bf16_t)tile[tx][ty + i];
}

// ---------------------------------------------------------------------------
// m97-style GEMM: D[M,N] = A[M,K] @ Bt[N,K]^T + bias
// ---------------------------------------------------------------------------
template <int STORE_MODE>
__global__ __launch_bounds__(256) void gemm_bt_128(
    const bf16_t* __restrict__ A, const bf16_t* __restrict__ Bt,
    const float* __restrict__ bias, void* __restrict__ Dout,
    int M, int N, int K) {
  __shared__ bf16_t As[128 * 32];
  __shared__ bf16_t Bs[128 * 32];
  const int tid = threadIdx.x;
  const int lane = tid & 63;
  const int w = tid >> 6;
  const int wr = w >> 1, wc = w & 1;
  const int m0 = blockIdx.y * 128, n0 = blockIdx.x * 128;

  f32x4 acc[4][4] = {};

  const int r0 = tid >> 2;
  const int kk = (tid & 3) * 8;
  const int fr = lane & 15;
  const int fk = (lane >> 4) * 8;

  for (int k0 = 0; k0 < K; k0 += 32) {
    load_lds16(A + (long)(m0 + r0) * K + k0 + kk, As + w * 512);
    load_lds16(A + (long)(m0 + 64 + r0) * K + k0 + kk, As + 2048 + w * 512);
    load_lds16(Bt + (long)(n0 + r0) * K + k0 + kk, Bs + w * 512);
    load_lds16(Bt + (long)(n0 + 64 + r0) * K + k0 + kk, Bs + 2048 + w * 512);
    asm volatile("s_waitcnt vmcnt(0)" ::: "memory");
    __syncthreads();

    bf16x8 af[4], bfx[4];
#pragma unroll
    for (int m = 0; m < 4; ++m)
      af[m] = *(const bf16x8*)&As[(wr * 64 + m * 16 + fr) * 32 + fk];
#pragma unroll
    for (int n = 0; n < 4; ++n)
      bfx[n] = *(const bf16x8*)&Bs[(wc * 64 + n * 16 + fr) * 32 + fk];
#pragma unroll
    for (int m = 0; m < 4; ++m)
#pragma unroll
      for (int n = 0; n < 4; ++n)
        acc[m][n] = __builtin_amdgcn_mfma_f32_16x16x32_bf16(af[m], bfx[n],
                                                            acc[m][n], 0, 0, 0);
    __syncthreads();
  }

  const int fq = lane >> 4;
#pragma unroll
  for (int m = 0; m < 4; ++m) {
#pragma unroll
    for (int n = 0; n < 4; ++n) {
      int col = n0 + wc * 64 + n * 16 + fr;
      float bv = bias[col];
#pragma unroll
      for (int r = 0; r < 4; ++r) {
        int row = m0 + wr * 64 + m * 16 + fq * 4 + r;
        float v = acc[m][n][r] + bv;
        if (STORE_MODE == 0)
          ((float*)Dout)[(long)row * N + col] = v;
        else
          ((bf16_t*)Dout)[(long)row * N + col] = (bf16_t)v;
      }
    }
  }
}

// ---------------------------------------------------------------------------
// LDS half-barrier (4 waves): monotonic counter, release add / acquire spin.
// ---------------------------------------------------------------------------
__device__ __forceinline__ void half_bar(unsigned int* c, unsigned int target,
                                         int lane) {
  if (lane == 0)
    __hip_atomic_fetch_add(c, 1u, __ATOMIC_RELEASE,
                           __HIP_MEMORY_SCOPE_WORKGROUP);
  unsigned int v;
  do {
    v = __hip_atomic_load(c, __ATOMIC_ACQUIRE, __HIP_MEMORY_SCOPE_WORKGROUP);
    if (v >= target) break;
    __builtin_amdgcn_s_sleep(1);
  } while (true);
}

// ---------------------------------------------------------------------------
// Persistent recurrence v10 = v9 MINUS the dangling self-prefetch (r11 crash:
// un-waited global_load into a compiler-dead register -> VGPR corruption).
//  - exponential poll backoff (cut L3 poll traffic ~3x)
//  - wave0-only epilogue: 16B stores (64 msgs vs 256), ONE LDS bar per step,
//    Z prefetch only wave 0 (Z traffic /4); waves 1-3 go straight to the
//    next poll.  sred WAR guarded by LDS epoch ctr sfree.
//  - chains phase-staggered at t=0 (anti-phase resource bursts)
// Topology/protocol from v8 (proven): 256 WGs x 512 thr, two 16-row chains
// per WG sharing one 128 KB W-LDS slice; h stores sc0sc1 write-through;
// A loads sc0; relaxed agent flags; NO fences anywhere.
// ---------------------------------------------------------------------------
__global__ __launch_bounds__(512, 1) void rnn_persistent10(
    const bf16_t* __restrict__ h0,
    bf16_t* __restrict__ Hbuf,        // Z in, h out, (T,B,H) bf16
    const bf16_t* __restrict__ WhhT,  // (2048 cols, 2048 K) bf16
    unsigned int* __restrict__ flags) {  // 512 flags, 64B apart, pre-zeroed
  __shared__ bf16_t Wlds[65536];          // 128 KB
  __shared__ float sred[2][4][16 * 36];   // 18.4 KB
  __shared__ unsigned int barc[2];        // per-half barrier counters
  __shared__ unsigned int sfree[2];       // per-half sred-consumed epoch

  const int tid = threadIdx.x, lane = tid & 63, w = tid >> 6;
  const int h = w >> 2;               // half 0/1
  const int lw = w & 3;               // wave within half
  const int gid = blockIdx.x;
  const int p = (gid >> 1) & 3;
  const int n0idx = ((gid & 1) << 5) | (gid >> 3);  // 0..63
  const int chain = p + h * 4;        // row group 0..7
  const int m0 = chain * 16, n0 = n0idx * 32;
  const int H = 2048;
  const long BH = 128L * 2048;
  const int kb = lw * 512;            // wave K-slab
  const int fr = lane & 15, fg = lane >> 4;
  const int w64 = lw * 64;            // k8 base of slab

  // ---- stage W cols [n0, n0+32) into LDS (once, all 512 threads) ----
  {
    const int scol = tid >> 4;          // 0..31
    const int sk16 = tid & 15;
    const bf16_t* gsrc = WhhT + (long)(n0 + scol) * H + sk16 * 8;
#pragma unroll 4
    for (int j = 0; j < 16; ++j) {
      bf16x8 v = *(const bf16x8*)(gsrc + j * 128);
      int k8 = sk16 + j * 16;
      *(bf16x8*)&Wlds[(k8 * 32 + scol) * 8] = v;
    }
  }
  if (tid < 2) { barc[tid] = 0; sfree[tid] = 0; }
  __syncthreads();  // ONLY whole-WG barrier; halves decoupled after this

  // anti-phase stagger: half 1 starts ~1.7us late (chains are independent)
  if (h == 1) __builtin_amdgcn_s_sleep(64);

  // wave0 epilogue ownership: lane e -> row e>>2 (0..15), cols (e&3)*8..+8
  const int zrowW = lane >> 2, zcolW = (lane & 3) * 8;
  const int sidx = zrowW * 36 + zcolW;
  const long zoffW = (long)(m0 + zrowW) * H + n0 + zcolW;

  unsigned int* myflag = flags + (((chain << 6) | n0idx) << 4);
  const unsigned int* pollflag =
      flags + (((chain << 6) | (lw * 16 + (lane & 15))) << 4);
  unsigned int* bc = &barc[h];
  unsigned int* sf = &sfree[h];

  for (int t = 0; t < 256; ++t) {
    const bf16_t* hp = (t == 0) ? h0 : Hbuf + (long)(t - 1) * BH;
    bf16_t* z = Hbuf + (long)t * BH;

    // ---- Z prefetch (wave 0 only, 16B/lane, sc0sc1): hides under poll ----
    f32x4 zvr;
    if (lw == 0) {
      const bf16_t* zp = z + zoffW;
      asm volatile("global_load_dwordx4 %0, %1, off sc0 sc1"
                   : "=v"(zvr)
                   : "v"(zp)
                   : "memory");
    }

    // ---- poll my K-slab's 16 producer flags, exponential backoff ----
    if (t > 0) {
      const unsigned int tt = (unsigned int)t;
      unsigned int v = __hip_atomic_load(pollflag, __ATOMIC_RELAXED,
                                         __HIP_MEMORY_SCOPE_AGENT);
      if (!__all(v >= tt)) {
        __builtin_amdgcn_s_sleep(2);
        v = __hip_atomic_load(pollflag, __ATOMIC_RELAXED,
                              __HIP_MEMORY_SCOPE_AGENT);
        if (!__all(v >= tt)) {
          __builtin_amdgcn_s_sleep(4);
          v = __hip_atomic_load(pollflag, __ATOMIC_RELAXED,
                                __HIP_MEMORY_SCOPE_AGENT);
          if (!__all(v >= tt)) {
            __builtin_amdgcn_s_sleep(8);
            v = __hip_atomic_load(pollflag, __ATOMIC_RELAXED,
                                  __HIP_MEMORY_SCOPE_AGENT);
            while (!__all(v >= tt)) {
              __builtin_amdgcn_s_sleep(16);
              v = __hip_atomic_load(pollflag, __ATOMIC_RELAXED,
                                    __HIP_MEMORY_SCOPE_AGENT);
            }
          }
        }
      }
    }

    // ---- A-frags: 16 rows (fr) x K-slab 512, sc0 (L2-cacheable) ----
    const bf16_t* Ab = hp + (long)(m0 + fr) * H + kb + fg * 8;
    f32x4 a0, a1, a2, a3, a4, a5, a6, a7, a8, a9, a10, a11, a12, a13, a14, a15;
    asm volatile(
        "global_load_dwordx4 %0, %16, off sc0\n\t"
        "global_load_dwordx4 %1, %16, off offset:64 sc0\n\t"
        "global_load_dwordx4 %2, %16, off offset:128 sc0\n\t"
        "global_load_dwordx4 %3, %16, off offset:192 sc0\n\t"
        "global_load_dwordx4 %4, %16, off offset:256 sc0\n\t"
        "global_load_dwordx4 %5, %16, off offset:320 sc0\n\t"
        "global_load_dwordx4 %6, %16, off offset:384 sc0\n\t"
        "global_load_dwordx4 %7, %16, off offset:448 sc0\n\t"
        "global_load_dwordx4 %8, %16, off offset:512 sc0\n\t"
        "global_load_dwordx4 %9, %16, off offset:576 sc0\n\t"
        "global_load_dwordx4 %10, %16, off offset:640 sc0\n\t"
        "global_load_dwordx4 %11, %16, off offset:704 sc0\n\t"
        "global_load_dwordx4 %12, %16, off offset:768 sc0\n\t"
        "global_load_dwordx4 %13, %16, off offset:832 sc0\n\t"
        "global_load_dwordx4 %14, %16, off offset:896 sc0\n\t"
        "global_load_dwordx4 %15, %16, off offset:960 sc0\n\t"
        "s_waitcnt vmcnt(0)"
        : "=&v"(a0), "=&v"(a1), "=&v"(a2), "=&v"(a3), "=&v"(a4), "=&v"(a5),
          "=&v"(a6), "=&v"(a7), "=&v"(a8), "=&v"(a9), "=&v"(a10), "=&v"(a11),
          "=&v"(a12), "=&v"(a13), "=&v"(a14), "=&v"(a15)
        : "v"(Ab)
        : "memory");
    __builtin_amdgcn_sched_barrier(0);  // keep MFMA after the wait

    f32x4 acc0 = {}, acc1 = {};
#define STEPX(ks, A)                                                          \
  {                                                                           \
    bf16x8 w0 = *(const bf16x8*)&Wlds[((w64 + (ks) * 4 + fg) * 32 + fr) * 8]; \
    bf16x8 w1 =                                                               \
        *(const bf16x8*)&Wlds[((w64 + (ks) * 4 + fg) * 32 + 16 + fr) * 8];    \
    bf16x8 av = __builtin_bit_cast(bf16x8, A);                                \
    acc0 = __builtin_amdgcn_mfma_f32_16x16x32_bf16(av, w0, acc0, 0, 0, 0);    \
    acc1 = __builtin_amdgcn_mfma_f32_16x16x32_bf16(av, w1, acc1, 0, 0, 0);    \
  }
    STEPX(0, a0)   STEPX(1, a1)   STEPX(2, a2)   STEPX(3, a3)
    STEPX(4, a4)   STEPX(5, a5)   STEPX(6, a6)   STEPX(7, a7)
    STEPX(8, a8)   STEPX(9, a9)   STEPX(10, a10) STEPX(11, a11)
    STEPX(12, a12) STEPX(13, a13) STEPX(14, a14) STEPX(15, a15)
#undef STEPX

    // ---- WAR guard: wave0 must have consumed sred of step t-1 ----
    if (t > 0) {
      while (__hip_atomic_load(sf, __ATOMIC_ACQUIRE,
                               __HIP_MEMORY_SCOPE_WORKGROUP) <
             (unsigned int)t)
        __builtin_amdgcn_s_sleep(1);
    }

    // ---- write per-wave partials (padded stride 36) ----
#pragma unroll
    for (int rr = 0; rr < 4; ++rr) {
      sred[h][lw][(fg * 4 + rr) * 36 + fr] = acc0[rr];
      sred[h][lw][(fg * 4 + rr) * 36 + 16 + fr] = acc1[rr];
    }
    half_bar(bc, (unsigned int)(t + 1) * 4, lane);

    // ---- wave0-only epilogue: reduce + Z + relu + 16B store + flag ----
    if (lw == 0) {
      f32x4 slo = *(const f32x4*)&sred[h][0][sidx];
      f32x4 shi = *(const f32x4*)&sred[h][0][sidx + 4];
#pragma unroll
      for (int ww = 1; ww < 4; ++ww) {
        slo = slo + *(const f32x4*)&sred[h][ww][sidx];
        shi = shi + *(const f32x4*)&sred[h][ww][sidx + 4];
      }
      bf16x8 zv = __builtin_bit_cast(bf16x8, zvr);
      bf16x8 o;
#pragma unroll
      for (int c = 0; c < 4; ++c) {
        float v0 = slo[c] + (float)zv[c];
        float v1 = shi[c] + (float)zv[c + 4];
        o[c] = (bf16_t)(v0 > 0.f ? v0 : 0.f);
        o[c + 4] = (bf16_t)(v1 > 0.f ? v1 : 0.f);
      }
      const bf16_t* zp = z + zoffW;
      {
        f32x4 ov = __builtin_bit_cast(f32x4, o);
        asm volatile("global_store_dwordx4 %0, %1, off sc0 sc1" ::"v"(zp),
                     "v"(ov)
                     : "memory");
      }
      asm volatile("s_waitcnt vmcnt(0)" ::: "memory");  // tile visible in L3
      if (lane == 0) {
        __hip_atomic_store(myflag, (unsigned int)(t + 1), __ATOMIC_RELAXED,
                           __HIP_MEMORY_SCOPE_AGENT);
        __hip_atomic_store(sf, (unsigned int)(t + 1), __ATOMIC_RELEASE,
                           __HIP_MEMORY_SCOPE_WORKGROUP);
      }
    }
  }
}

// ---------------------------------------------------------------------------
extern "C" void kernel_launch(void* const* d_in, const int* in_sizes, int n_in,
                              void* d_out, int out_size, void* d_ws,
                              size_t ws_size, hipStream_t stream) {
  const float* x   = (const float*)d_in[0];  // (T,B,D)
  const float* h0  = (const float*)d_in[1];  // (B,H)
  const float* Wxh = (const float*)d_in[2];  // (D,H)
  const float* Whh = (const float*)d_in[3];  // (H,H)
  const float* bh  = (const float*)d_in[4];  // (H,)
  const float* Whq = (const float*)d_in[5];  // (H,Q)
  const float* bq  = (const float*)d_in[6];  // (Q,)
  float* out = (float*)d_out;

  const int T = 256, B = 128, D = 1024, H = 2048, Q = 1024;
  const long MB = (long)T * B;  // 32768

  char* ws = (char*)d_ws;
  unsigned int* flags = (unsigned int*)ws;  ws += 512 * 64;  // padded flags
  bf16_t* x_bf = (bf16_t*)ws;  ws += MB * D * 2;             // 64 MiB
  bf16_t* Hbuf = (bf16_t*)ws;  ws += MB * H * 2;             // 128 MiB (Z->h)
  bf16_t* h0bf = (bf16_t*)ws;  ws += (long)B * H * 2;
  bf16_t* WxhT = (bf16_t*)ws;  ws += (long)H * D * 2;
  bf16_t* WhhT = (bf16_t*)ws;  ws += (long)H * H * 2;
  bf16_t* WhqT = (bf16_t*)ws;  ws += (long)Q * H * 2;

  hipMemsetAsync(flags, 0, 512 * 64, stream);

  // --- convert inputs to bf16 (weights transposed to N x K) ---
  conv_f32_bf16<<<(int)(MB * D / 8 / 256), 256, 0, stream>>>(x, x_bf, MB * D);
  conv_f32_bf16<<<(int)((long)B * H / 8 / 256), 256, 0, stream>>>(h0, h0bf,
                                                                  (long)B * H);
  transpose_conv<<<dim3(H / 32, D / 32), dim3(32, 8), 0, stream>>>(Wxh, WxhT, D, H);
  transpose_conv<<<dim3(H / 32, H / 32), dim3(32, 8), 0, stream>>>(Whh, WhhT, H, H);
  transpose_conv<<<dim3(Q / 32, H / 32), dim3(32, 8), 0, stream>>>(Whq, WhqT, H, Q);

  // --- Z = x @ W_xh + b_h  (all timesteps), bf16 into Hbuf ---
  gemm_bt_128<1><<<dim3(H / 128, MB / 128), 256, 0, stream>>>(
      x_bf, WxhT, bh, Hbuf, (int)MB, H, D);

  // --- entire recurrence: ONE persistent kernel, 2 staggered chains/WG ---
  rnn_persistent10<<<256, 512, 0, stream>>>(h0bf, Hbuf, WhhT, flags);

  // --- out = H @ W_hq + b_q  (fp32 straight to d_out) ---
  gemm_bt_128<0><<<dim3(Q / 128, MB / 128), 256, 0, stream>>>(
      Hbuf, WhqT, bq, out, (int)MB, Q, H);

  // --- final h (fp32) appended after (T*B, Q) block ---
  conv_bf16_f32<<<(int)((long)B * H / 256), 256, 0, stream>>>(
      Hbuf + (long)(T - 1) * B * H, out + MB * Q, (long)B * H);
}